// Round 14
// baseline (255.968 us; speedup 1.0000x reference)
//
#include <hip/hip_runtime.h>
#include <hip/hip_fp16.h>

// OTK (optimal-transport kernel attention) for MI355X.
// Pipeline (r14):
//   k1:  E = exp(-10*C*pf) from x,w (fp16 MFMA) — standalone, full chip.
//   k20: fused — blocks 0..63 run Sinkhorn (k2) with HALF of E manually
//        spilled to a 128KB LDS cache (halves L2 bytes/iter); blocks
//        64..1087 transpose x -> xT on the other 192 CUs (free under k2).
//   k3:  out = Pt @ xT (fp16 MFMA, 256-thr blocks, register prefetch).
// Identity: lse_m(K+u+v) = u + lse_m(K+v)  =>  plain Sinkhorn on E=exp(K).
//
// k2 lesson bank (r1-r13): the RA never carries E in registers (92-reg cap
// at 512 thr; pins spill; fused bodies hit scratch; waves_per_eu no-op for
// budget). k2 is L2-bytes-per-CU bound (~190 GB/s/CU plateau). So: do the
// spill OURSELVES into LDS — per-thread private slots (no barrier needed),
// XOR-swizzled 16B chunks (bank = ((j^(t&7))*4)%32, 2 lanes/bank = free).

typedef _Float16 h2 __attribute__((ext_vector_type(2)));
typedef _Float16 h8 __attribute__((ext_vector_type(8)));
typedef float f4 __attribute__((ext_vector_type(4)));

#define NB 16
#define NN 2048
#define ND 512
#define NH 4
#define NM 64
#define NITER 30
#define EUSCALE 8.0f   // keeps fp16(eu*EUSCALE) in normal range (eu >= ~1e-5)

static __device__ __forceinline__ float fdot2f(h2 a, h2 b, float c) {
#if __has_builtin(__builtin_amdgcn_fdot2)
  return __builtin_amdgcn_fdot2(a, b, c, false);
#else
  return (float)a[0] * (float)b[0] + (float)a[1] * (float)b[1] + c;
#endif
}

static __device__ __forceinline__ h2 pkrtz(float a, float b) {
  return __builtin_bit_cast(h2, __builtin_amdgcn_cvt_pkrtz(a, b));
}

static __device__ __forceinline__ h8 pack8(float4 a, float4 b) {
  h8 r;
  r[0] = (_Float16)a.x; r[1] = (_Float16)a.y; r[2] = (_Float16)a.z; r[3] = (_Float16)a.w;
  r[4] = (_Float16)b.x; r[5] = (_Float16)b.y; r[6] = (_Float16)b.z; r[7] = (_Float16)b.w;
  return r;
}

static __device__ __forceinline__ float sq4(float4 a) {
  return a.x * a.x + a.y * a.y + a.z * a.z + a.w * a.w;
}

// ------------------------------------------------------------- k1: build E
__global__ __launch_bounds__(512) void k1_buildE(const float* __restrict__ x,
                                                 const float* __restrict__ w,
                                                 _Float16* __restrict__ E) {
  __shared__ _Float16 Ah[128][72];
  __shared__ _Float16 Bh[256][72];
  __shared__ float x2s[128][4];
  __shared__ float w2s[256][2];
  __shared__ float x2r[128];
  __shared__ float w2r[256];

  const int b = blockIdx.y;
  const int n0 = blockIdx.x * 128;
  const int tid = threadIdx.x;
  const int lane = tid & 63;
  const int wv = tid >> 6;
  const int lrow = lane & 15;
  const int kq = lane >> 4;

  f4 acc[16];
#pragma unroll
  for (int i = 0; i < 16; ++i) acc[i] = (f4){0.f, 0.f, 0.f, 0.f};

  const int ar = tid >> 2, ac = (tid & 3) * 16;
  const int br = tid >> 1, bc = (tid & 1) * 32;
  const float* xsrc = x + ((size_t)(b * NN + n0 + ar) * ND + ac);
  const float* wsrc = w + ((size_t)br * ND + bc);
  float x2p = 0.f, w2p = 0.f;

  for (int kt = 0; kt < 8; ++kt) {
    {
      const float4* s4 = (const float4*)(xsrc + kt * 64);
      float4 a0 = s4[0], a1 = s4[1], a2 = s4[2], a3 = s4[3];
      x2p += sq4(a0) + sq4(a1) + sq4(a2) + sq4(a3);
      *(h8*)&Ah[ar][ac] = pack8(a0, a1);
      *(h8*)&Ah[ar][ac + 8] = pack8(a2, a3);
    }
    {
      const float4* s4 = (const float4*)(wsrc + kt * 64);
      float4 u0 = s4[0], u1 = s4[1], u2 = s4[2], u3 = s4[3];
      float4 u4 = s4[4], u5 = s4[5], u6 = s4[6], u7 = s4[7];
      w2p += sq4(u0) + sq4(u1) + sq4(u2) + sq4(u3)
           + sq4(u4) + sq4(u5) + sq4(u6) + sq4(u7);
      *(h8*)&Bh[br][bc] = pack8(u0, u1);
      *(h8*)&Bh[br][bc + 8] = pack8(u2, u3);
      *(h8*)&Bh[br][bc + 16] = pack8(u4, u5);
      *(h8*)&Bh[br][bc + 24] = pack8(u6, u7);
    }
    __syncthreads();
#pragma unroll
    for (int s = 0; s < 2; ++s) {
      h8 af = *(const h8*)&Ah[wv * 16 + lrow][s * 32 + kq * 8];
#pragma unroll
      for (int cf = 0; cf < 16; ++cf) {
        h8 bf = *(const h8*)&Bh[cf * 16 + lrow][s * 32 + kq * 8];
        acc[cf] = __builtin_amdgcn_mfma_f32_16x16x32_f16(af, bf, acc[cf], 0, 0, 0);
      }
    }
    __syncthreads();
  }

  x2s[ar][tid & 3] = x2p;
  w2s[br][tid & 1] = w2p;
  __syncthreads();
  if (tid < 128) {
    x2r[tid] = x2s[tid][0] + x2s[tid][1] + x2s[tid][2] + x2s[tid][3];
  } else if (tid < 384) {
    const int r = tid - 128;
    w2r[r] = w2s[r][0] + w2s[r][1];
  }
  __syncthreads();

#pragma unroll
  for (int cf = 0; cf < 16; ++cf) {
    const int mg = cf * 16 + lrow;
    const int hh = mg >> 6;
    const int m = mg & 63;
    const float w2v = w2r[mg];
    const float bm = (float)m * (1.0f / 64.0f);
    _Float16* Eb = E + ((size_t)(b * NH + hh) * NN) * NM;
#pragma unroll
    for (int j = 0; j < 4; ++j) {
      const int nl = wv * 16 + kq * 4 + j;
      const int n = n0 + nl;
      const float c2 = x2r[nl] + w2v - 2.0f * acc[cf][j];
      const float Cd = sqrtf(fmaxf(c2, 0.0f));
      const float tt = (float)n * (1.0f / 2048.0f) - bm;
      const float pf = __expf(-100.0f * tt * tt);
      const float Ev = __expf(-10.0f * Cd * pf);
      Eb[(size_t)n * NM + m] = (_Float16)Ev;
    }
  }
}

// ----------------------------------------- k20: fused Sinkhorn | transpose
// blocks 0..63: k2 role. Dynamic LDS layout:
//   Ech : uint4[1024][8] @ 0       (131072 B) slot s=2t+i, chunk at j^(t&7)
//   evf : float[64]      @ 131072
//   evh : h2[32]         @ 131328
//   pbuf: uint[512]      @ 131456  -> total 133504
// blocks 64..1087: k0 role, 4 transpose tiles (2 passes x 2), uses
//   float tile[128][65] (33280 B) at smem base.
__global__ __launch_bounds__(512) void k20_fused(const float* __restrict__ x,
                                                 const _Float16* __restrict__ E,
                                                 _Float16* __restrict__ xT,
                                                 _Float16* __restrict__ Pt) {
  extern __shared__ __align__(16) char smem[];
  const int bid = blockIdx.x;
  const int tid = threadIdx.x;

  if (bid >= 64) {
    // ---------------- k0 role: 4 tiles (2 passes of 2) ----------------
    auto tile = (float(*)[65])smem;
    const int sub = tid >> 8;
    const int t = tid & 255;
    const int bid2 = bid - 64;
#pragma unroll
    for (int p = 0; p < 2; ++p) {
      if (p) __syncthreads();
      const int t4 = bid2 * 4 + p * 2 + sub;   // 0..4095
      const int b = t4 >> 8;
      const int rem = t4 & 255;
      const int n0 = (rem & 31) * 64;
      const int d0 = (rem >> 5) * 64;
      const int rbase = sub << 6;
      const int nr = t >> 2;
      const int ds = (t & 3) * 16;
      const float4* src = (const float4*)(x + ((size_t)(b * NN + n0 + nr) * ND + d0 + ds));
      float4 v0 = src[0], v1 = src[1], v2 = src[2], v3 = src[3];
      float vals[16] = {v0.x, v0.y, v0.z, v0.w, v1.x, v1.y, v1.z, v1.w,
                        v2.x, v2.y, v2.z, v2.w, v3.x, v3.y, v3.z, v3.w};
#pragma unroll
      for (int j = 0; j < 16; ++j) tile[rbase + ds + j][nr] = vals[j];
      __syncthreads();
      const int dr = t >> 2;
      const int ns = (t & 3) * 16;
      h8 o0, o1;
#pragma unroll
      for (int j = 0; j < 8; ++j) o0[j] = (_Float16)tile[rbase + dr][ns + j];
#pragma unroll
      for (int j = 0; j < 8; ++j) o1[j] = (_Float16)tile[rbase + dr][ns + 8 + j];
      _Float16* dst = xT + ((size_t)(b * ND + d0 + dr) * NN + n0 + ns);
      *(h8*)dst = o0;
      *(h8*)(dst + 8) = o1;
    }
    return;
  }

  // ------------------------- k2 role: Sinkhorn -------------------------
  const int bh = bid;
  const int b = bh >> 2, h = bh & 3;
  const int lane = tid & 63;

  uint4* Ech = (uint4*)smem;
  float* evf = (float*)(smem + 131072);
  h2* evh = (h2*)(smem + 131328);
  unsigned int* pbuf = (unsigned int*)(smem + 131456);

  const _Float16* Ep = E + (size_t)bh * (NN * NM);
  const int sw = tid & 7;

  // stage rows 4t, 4t+1 into private LDS slots 2t, 2t+1 (swizzled chunks)
#pragma unroll
  for (int i = 0; i < 2; ++i) {
    const uint4* src = (const uint4*)(Ep + (size_t)(4 * tid + i) * NM);
    uint4* dst = Ech + (size_t)(2 * tid + i) * 8;
#pragma unroll
    for (int j = 0; j < 8; ++j) dst[j ^ sw] = src[j];
  }

  float eu[4] = {1.f, 1.f, 1.f, 1.f};
  if (tid < 64) evf[tid] = 1.f;
  if (tid < 32) evh[tid] = pkrtz(1.f, 1.f);
  __syncthreads();

#pragma unroll 1
  for (int it = 0; it < NITER; ++it) {
    asm volatile("" ::: "memory");
    // ev broadcast (fp16-packed master in LDS)
    h2 evr[32];
    {
      const uint4* ev4 = (const uint4*)evh;
#pragma unroll
      for (int q8 = 0; q8 < 8; ++q8) {
        uint4 v = ev4[q8];
        evr[q8 * 4 + 0] = __builtin_bit_cast(h2, v.x);
        evr[q8 * 4 + 1] = __builtin_bit_cast(h2, v.y);
        evr[q8 * 4 + 2] = __builtin_bit_cast(h2, v.z);
        evr[q8 * 4 + 3] = __builtin_bit_cast(h2, v.w);
      }
    }
    // build e[4][32]: rows 0,1 from LDS cache; rows 2,3 from L2
    h2 e[4][32];
#pragma unroll
    for (int i = 0; i < 2; ++i) {
      const uint4* slot = Ech + (size_t)(2 * tid + i) * 8;
#pragma unroll
      for (int j = 0; j < 8; ++j) {
        uint4 v = slot[j ^ sw];
        e[i][j * 4 + 0] = __builtin_bit_cast(h2, v.x);
        e[i][j * 4 + 1] = __builtin_bit_cast(h2, v.y);
        e[i][j * 4 + 2] = __builtin_bit_cast(h2, v.z);
        e[i][j * 4 + 3] = __builtin_bit_cast(h2, v.w);
      }
    }
#pragma unroll
    for (int i = 2; i < 4; ++i) {
      const uint4* src = (const uint4*)(Ep + (size_t)(4 * tid + i) * NM);
#pragma unroll
      for (int j = 0; j < 8; ++j) {
        uint4 v = src[j];
        e[i][j * 4 + 0] = __builtin_bit_cast(h2, v.x);
        e[i][j * 4 + 1] = __builtin_bit_cast(h2, v.y);
        e[i][j * 4 + 2] = __builtin_bit_cast(h2, v.z);
        e[i][j * 4 + 3] = __builtin_bit_cast(h2, v.w);
      }
    }
    // u-pass: S[n] = sum_m E*ev ; eu = (1/N)/(eu*S). 8 chains for ILP.
    float sa[4] = {0.f, 0.f, 0.f, 0.f};
    float sb[4] = {0.f, 0.f, 0.f, 0.f};
#pragma unroll
    for (int q = 0; q < 16; ++q) {
#pragma unroll
      for (int i = 0; i < 4; ++i) sa[i] = fdot2f(e[i][q], evr[q], sa[i]);
    }
#pragma unroll
    for (int q = 16; q < 32; ++q) {
#pragma unroll
      for (int i = 0; i < 4; ++i) sb[i] = fdot2f(e[i][q], evr[q], sb[i]);
    }
#pragma unroll
    for (int i = 0; i < 4; ++i) {
      eu[i] = 4.8828125e-4f * __builtin_amdgcn_rcpf(eu[i] * (sa[i] + sb[i]));
    }
    // v-pass local: T'[m] = sum_rows E * (eu*EUSCALE)
    h2 eup[4];
#pragma unroll
    for (int i = 0; i < 4; ++i) {
      const float es = eu[i] * EUSCALE;
      eup[i] = pkrtz(es, es);
    }
    h2 tp[32];
#pragma unroll
    for (int q = 0; q < 32; ++q) {
      tp[q] = e[0][q] * eup[0] + e[1][q] * eup[1];
      tp[q] += e[2][q] * eup[2] + e[3][q] * eup[3];
    }
    // register-halving butterfly -> lane l holds col-pair bitrev5(l&31)
#pragma unroll
    for (int k = 0; k < 5; ++k) {
      const int nn = 32 >> k;
      const bool up = (lane >> k) & 1;
#pragma unroll
      for (int p = 0; p < (nn >> 1); ++p) {
        h2 keep = up ? tp[p + (nn >> 1)] : tp[p];
        h2 send = up ? tp[p] : tp[p + (nn >> 1)];
        int rv = __shfl_xor(__builtin_bit_cast(int, send), 1 << k, 64);
        tp[p] = keep + __builtin_bit_cast(h2, rv);
      }
    }
    pbuf[tid] = __builtin_bit_cast(unsigned int, tp[0]);
    __syncthreads();
    if (tid < 32) {
      const int j = tid;
      const int rev = ((j & 1) << 4) | ((j & 2) << 2) | (j & 4) | ((j & 8) >> 2) | ((j & 16) >> 4);
      float T0 = 0.f, T1 = 0.f;
#pragma unroll
      for (int wq = 0; wq < 8; ++wq) {
        h2 a = __builtin_bit_cast(h2, pbuf[wq * 64 + rev]);
        h2 c = __builtin_bit_cast(h2, pbuf[wq * 64 + rev + 32]);
        T0 += (float)a[0] + (float)c[0];
        T1 += (float)a[1] + (float)c[1];
      }
      const float e0 = evf[2 * j], e1 = evf[2 * j + 1];
      const float n0 = EUSCALE * __builtin_amdgcn_rcpf(e0 * T0);
      const float n1 = EUSCALE * __builtin_amdgcn_rcpf(e1 * T1);
      evf[2 * j] = n0;
      evf[2 * j + 1] = n1;
      evh[j] = pkrtz(n0, n1);
    }
    __syncthreads();
  }

  // epilogue: rebuild e (LDS + L2), P = E*eu*ev, 8B packed stores.
  asm volatile("" ::: "memory");
  h2 ee[4][32];
#pragma unroll
  for (int i = 0; i < 2; ++i) {
    const uint4* slot = Ech + (size_t)(2 * tid + i) * 8;
#pragma unroll
    for (int j = 0; j < 8; ++j) {
      uint4 v = slot[j ^ sw];
      ee[i][j * 4 + 0] = __builtin_bit_cast(h2, v.x);
      ee[i][j * 4 + 1] = __builtin_bit_cast(h2, v.y);
      ee[i][j * 4 + 2] = __builtin_bit_cast(h2, v.z);
      ee[i][j * 4 + 3] = __builtin_bit_cast(h2, v.w);
    }
  }
#pragma unroll
  for (int i = 2; i < 4; ++i) {
    const uint4* src = (const uint4*)(Ep + (size_t)(4 * tid + i) * NM);
#pragma unroll
    for (int j = 0; j < 8; ++j) {
      uint4 v = src[j];
      ee[i][j * 4 + 0] = __builtin_bit_cast(h2, v.x);
      ee[i][j * 4 + 1] = __builtin_bit_cast(h2, v.y);
      ee[i][j * 4 + 2] = __builtin_bit_cast(h2, v.z);
      ee[i][j * 4 + 3] = __builtin_bit_cast(h2, v.w);
    }
  }
  _Float16* Pb = Pt + ((size_t)(b * 256 + h)) * NN;
#pragma unroll
  for (int q = 0; q < 32; ++q) {
    const float ev0 = evf[2 * q];
    const float ev1 = evf[2 * q + 1];
    float a0[4], a1[4];
#pragma unroll
    for (int i = 0; i < 4; ++i) {
      a0[i] = (float)ee[i][q][0] * eu[i] * ev0;   // row 4t+i, col 2q
      a1[i] = (float)ee[i][q][1] * eu[i] * ev1;   // row 4t+i, col 2q+1
    }
    uint2 st0, st1;
    st0.x = __builtin_bit_cast(unsigned int, pkrtz(a0[0], a0[1]));
    st0.y = __builtin_bit_cast(unsigned int, pkrtz(a0[2], a0[3]));
    st1.x = __builtin_bit_cast(unsigned int, pkrtz(a1[0], a1[1]));
    st1.y = __builtin_bit_cast(unsigned int, pkrtz(a1[2], a1[3]));
    *(uint2*)(Pb + (size_t)(2 * q) * 4 * NN + 4 * tid) = st0;
    *(uint2*)(Pb + (size_t)(2 * q + 1) * 4 * NN + 4 * tid) = st1;
  }
}

// ------------------------------------------------------------- k3: out GEMM
// 256 threads, 64x64 output tile, grid (8,4,16)=512 blocks (2/CU), register
// prefetch of the next K-tile hides global-load latency under the MFMAs.
__global__ __launch_bounds__(256) void k3_out(const _Float16* __restrict__ Pt,
                                              const _Float16* __restrict__ xT,
                                              float* __restrict__ out) {
  __shared__ _Float16 As[64][72];
  __shared__ _Float16 Bs[64][72];
  const int b = blockIdx.z;
  const int hf = blockIdx.y;
  const int dt = blockIdx.x;
  const int tid = threadIdx.x;
  const int lane = tid & 63;
  const int wv = tid >> 6;
  const int lrow = lane & 15;
  const int kq = lane >> 4;

  f4 acc[4];
#pragma unroll
  for (int i = 0; i < 4; ++i) acc[i] = (f4){0.f, 0.f, 0.f, 0.f};

  const int ar = tid >> 2, ac = (tid & 3) * 16;
  const _Float16* asrc = Pt + ((size_t)(b * 256 + hf * 64 + ar) * NN + ac);
  const _Float16* bsrc = xT + ((size_t)(b * ND + dt * 64 + ar) * NN + ac);

  h8 a0 = *(const h8*)(asrc);
  h8 a1 = *(const h8*)(asrc + 8);
  h8 b0 = *(const h8*)(bsrc);
  h8 b1 = *(const h8*)(bsrc + 8);

  for (int kt = 0; kt < 32; ++kt) {
    *(h8*)&As[ar][ac] = a0;
    *(h8*)&As[ar][ac + 8] = a1;
    *(h8*)&Bs[ar][ac] = b0;
    *(h8*)&Bs[ar][ac + 8] = b1;
    __syncthreads();
    if (kt < 31) {
      const int k0 = (kt + 1) * 64;
      a0 = *(const h8*)(asrc + k0);
      a1 = *(const h8*)(asrc + k0 + 8);
      b0 = *(const h8*)(bsrc + k0);
      b1 = *(const h8*)(bsrc + k0 + 8);
    }
#pragma unroll
    for (int s = 0; s < 2; ++s) {
      h8 af = *(const h8*)&As[wv * 16 + lrow][s * 32 + kq * 8];
#pragma unroll
      for (int cf = 0; cf < 4; ++cf) {
        h8 bf = *(const h8*)&Bs[cf * 16 + lrow][s * 32 + kq * 8];
        acc[cf] = __builtin_amdgcn_mfma_f32_16x16x32_f16(af, bf, acc[cf], 0, 0, 0);
      }
    }
    __syncthreads();
  }
#pragma unroll
  for (int cf = 0; cf < 4; ++cf) {
    const int d = dt * 64 + cf * 16 + lrow;
#pragma unroll
    for (int j = 0; j < 4; ++j) {
      const int row = hf * 64 + wv * 16 + kq * 4 + j;
      out[(size_t)(b * 256 + row) * ND + d] = acc[cf][j];
    }
  }
}

// ---------------------------------------------------------------- launcher
extern "C" void kernel_launch(void* const* d_in, const int* in_sizes, int n_in,
                              void* d_out, int out_size, void* d_ws, size_t ws_size,
                              hipStream_t stream) {
  const float* x = (const float*)d_in[0];
  const float* w = (const float*)d_in[1];
  float* out = (float*)d_out;
  char* ws = (char*)d_ws;
  // ws layout:
  //   xT : 16*512*2048 fp16 = 33,554,432 B
  //   E  : 16*4*2048*64 fp16 = 16,777,216 B
  //   Pt : 16*64*4*2048 fp16 = 16,777,216 B
  _Float16* xT = (_Float16*)ws;
  _Float16* E  = (_Float16*)(ws + (size_t)33554432);
  _Float16* Pt = (_Float16*)(ws + (size_t)50331648);

  // allow >64KB dynamic LDS for the fused kernel (133504 B used)
  (void)hipFuncSetAttribute((const void*)k20_fused,
                            hipFuncAttributeMaxDynamicSharedMemorySize, 135168);

  k1_buildE<<<dim3(16, NB), 512, 0, stream>>>(x, w, E);
  k20_fused<<<64 + 1024, 512, 133504, stream>>>(x, E, xT, Pt);
  k3_out<<<dim3(8, 4, NB), 256, 0, stream>>>(Pt, xT, out);
}

// Round 15
// 151.315 us; speedup vs baseline: 1.6916x; 1.6916x over previous
//
#include <hip/hip_runtime.h>
#include <hip/hip_fp16.h>

// OTK (optimal-transport kernel attention) for MI355X.
// Pipeline (r15):
//   k1:  E = exp(-10*C*pf) from x,w (fp16 MFMA) — standalone, full chip.
//   k20: fused — blocks 0..63 run Sinkhorn (r10 body VERBATIM, 80.3 us
//        measured x3); blocks 64..1087 transpose x -> xT (4 tiles each) on
//        the other ~192 CUs, fully hidden under the Sinkhorn shadow.
//        Static 33KB shared union -> 4 blocks/CU for both roles.
//   k3:  out = Pt @ xT (fp16 MFMA, 256-thr blocks, register prefetch).
// Identity: lse_m(K+u+v) = u + lse_m(K+v)  =>  plain Sinkhorn on E=exp(K).
//
// r14 lesson: LDS-caching E is a dead end — wave64 ds_read_b128 is
// inherently >=8 bank-cycles (1KB vs 128B/cy), so LDS BW/CU (~270 GB/s)
// barely beats the L2 path (~190 GB/s) and the 133KB footprint killed
// transpose occupancy (2.06M bank conflicts, 191 us). Keep the role-split
// overlap; drop the cache.
// k2 saga (r1-r12, closed): RA never carries E in registers; the remat
// streaming structure at 80 us is the practical floor for k2.

typedef _Float16 h2 __attribute__((ext_vector_type(2)));
typedef _Float16 h8 __attribute__((ext_vector_type(8)));
typedef float f4 __attribute__((ext_vector_type(4)));

#define NB 16
#define NN 2048
#define ND 512
#define NH 4
#define NM 64
#define NITER 30
#define EUSCALE 8.0f   // keeps fp16(eu*EUSCALE) in normal range (eu >= ~1e-5)

static __device__ __forceinline__ float fdot2f(h2 a, h2 b, float c) {
#if __has_builtin(__builtin_amdgcn_fdot2)
  return __builtin_amdgcn_fdot2(a, b, c, false);
#else
  return (float)a[0] * (float)b[0] + (float)a[1] * (float)b[1] + c;
#endif
}

static __device__ __forceinline__ h2 pkrtz(float a, float b) {
  return __builtin_bit_cast(h2, __builtin_amdgcn_cvt_pkrtz(a, b));
}

static __device__ __forceinline__ h8 pack8(float4 a, float4 b) {
  h8 r;
  r[0] = (_Float16)a.x; r[1] = (_Float16)a.y; r[2] = (_Float16)a.z; r[3] = (_Float16)a.w;
  r[4] = (_Float16)b.x; r[5] = (_Float16)b.y; r[6] = (_Float16)b.z; r[7] = (_Float16)b.w;
  return r;
}

static __device__ __forceinline__ float sq4(float4 a) {
  return a.x * a.x + a.y * a.y + a.z * a.z + a.w * a.w;
}

// ------------------------------------------------------------- k1: build E
__global__ __launch_bounds__(512) void k1_buildE(const float* __restrict__ x,
                                                 const float* __restrict__ w,
                                                 _Float16* __restrict__ E) {
  __shared__ _Float16 Ah[128][72];
  __shared__ _Float16 Bh[256][72];
  __shared__ float x2s[128][4];
  __shared__ float w2s[256][2];
  __shared__ float x2r[128];
  __shared__ float w2r[256];

  const int b = blockIdx.y;
  const int n0 = blockIdx.x * 128;
  const int tid = threadIdx.x;
  const int lane = tid & 63;
  const int wv = tid >> 6;
  const int lrow = lane & 15;
  const int kq = lane >> 4;

  f4 acc[16];
#pragma unroll
  for (int i = 0; i < 16; ++i) acc[i] = (f4){0.f, 0.f, 0.f, 0.f};

  const int ar = tid >> 2, ac = (tid & 3) * 16;
  const int br = tid >> 1, bc = (tid & 1) * 32;
  const float* xsrc = x + ((size_t)(b * NN + n0 + ar) * ND + ac);
  const float* wsrc = w + ((size_t)br * ND + bc);
  float x2p = 0.f, w2p = 0.f;

  for (int kt = 0; kt < 8; ++kt) {
    {
      const float4* s4 = (const float4*)(xsrc + kt * 64);
      float4 a0 = s4[0], a1 = s4[1], a2 = s4[2], a3 = s4[3];
      x2p += sq4(a0) + sq4(a1) + sq4(a2) + sq4(a3);
      *(h8*)&Ah[ar][ac] = pack8(a0, a1);
      *(h8*)&Ah[ar][ac + 8] = pack8(a2, a3);
    }
    {
      const float4* s4 = (const float4*)(wsrc + kt * 64);
      float4 u0 = s4[0], u1 = s4[1], u2 = s4[2], u3 = s4[3];
      float4 u4 = s4[4], u5 = s4[5], u6 = s4[6], u7 = s4[7];
      w2p += sq4(u0) + sq4(u1) + sq4(u2) + sq4(u3)
           + sq4(u4) + sq4(u5) + sq4(u6) + sq4(u7);
      *(h8*)&Bh[br][bc] = pack8(u0, u1);
      *(h8*)&Bh[br][bc + 8] = pack8(u2, u3);
      *(h8*)&Bh[br][bc + 16] = pack8(u4, u5);
      *(h8*)&Bh[br][bc + 24] = pack8(u6, u7);
    }
    __syncthreads();
#pragma unroll
    for (int s = 0; s < 2; ++s) {
      h8 af = *(const h8*)&Ah[wv * 16 + lrow][s * 32 + kq * 8];
#pragma unroll
      for (int cf = 0; cf < 16; ++cf) {
        h8 bf = *(const h8*)&Bh[cf * 16 + lrow][s * 32 + kq * 8];
        acc[cf] = __builtin_amdgcn_mfma_f32_16x16x32_f16(af, bf, acc[cf], 0, 0, 0);
      }
    }
    __syncthreads();
  }

  x2s[ar][tid & 3] = x2p;
  w2s[br][tid & 1] = w2p;
  __syncthreads();
  if (tid < 128) {
    x2r[tid] = x2s[tid][0] + x2s[tid][1] + x2s[tid][2] + x2s[tid][3];
  } else if (tid < 384) {
    const int r = tid - 128;
    w2r[r] = w2s[r][0] + w2s[r][1];
  }
  __syncthreads();

#pragma unroll
  for (int cf = 0; cf < 16; ++cf) {
    const int mg = cf * 16 + lrow;
    const int hh = mg >> 6;
    const int m = mg & 63;
    const float w2v = w2r[mg];
    const float bm = (float)m * (1.0f / 64.0f);
    _Float16* Eb = E + ((size_t)(b * NH + hh) * NN) * NM;
#pragma unroll
    for (int j = 0; j < 4; ++j) {
      const int nl = wv * 16 + kq * 4 + j;
      const int n = n0 + nl;
      const float c2 = x2r[nl] + w2v - 2.0f * acc[cf][j];
      const float Cd = sqrtf(fmaxf(c2, 0.0f));
      const float tt = (float)n * (1.0f / 2048.0f) - bm;
      const float pf = __expf(-100.0f * tt * tt);
      const float Ev = __expf(-10.0f * Cd * pf);
      Eb[(size_t)n * NM + m] = (_Float16)Ev;
    }
  }
}

// ----------------------------------------- k20: fused Sinkhorn | transpose
// Static shared union (33280 B -> 4 blocks/CU both roles):
//   k0-role: float tile[128][65]
//   k2-role: evf[64] f32, evh[32] h2, pbuf[512] u32
__global__ __launch_bounds__(512) void k20_fused(const float* __restrict__ x,
                                                 const _Float16* __restrict__ E,
                                                 _Float16* __restrict__ xT,
                                                 _Float16* __restrict__ Pt) {
  __shared__ union {
    float tile[128][65];
    struct {
      float evf[64];
      h2 evh[32];
      unsigned int pbuf[512];
    } s2;
  } sm;
  const int bid = blockIdx.x;
  const int tid = threadIdx.x;

  if (bid >= 64) {
    // ---------------- k0 role: 4 transpose tiles (2 passes of 2) --------
    auto tile = sm.tile;
    const int sub = tid >> 8;
    const int t = tid & 255;
    const int bid2 = bid - 64;
#pragma unroll
    for (int p = 0; p < 2; ++p) {
      if (p) __syncthreads();
      const int t4 = bid2 * 4 + p * 2 + sub;   // 0..4095
      const int b = t4 >> 8;
      const int rem = t4 & 255;
      const int n0 = (rem & 31) * 64;
      const int d0 = (rem >> 5) * 64;
      const int rbase = sub << 6;
      const int nr = t >> 2;
      const int ds = (t & 3) * 16;
      const float4* src = (const float4*)(x + ((size_t)(b * NN + n0 + nr) * ND + d0 + ds));
      float4 v0 = src[0], v1 = src[1], v2 = src[2], v3 = src[3];
      float vals[16] = {v0.x, v0.y, v0.z, v0.w, v1.x, v1.y, v1.z, v1.w,
                        v2.x, v2.y, v2.z, v2.w, v3.x, v3.y, v3.z, v3.w};
#pragma unroll
      for (int j = 0; j < 16; ++j) tile[rbase + ds + j][nr] = vals[j];
      __syncthreads();
      const int dr = t >> 2;
      const int ns = (t & 3) * 16;
      h8 o0, o1;
#pragma unroll
      for (int j = 0; j < 8; ++j) o0[j] = (_Float16)tile[rbase + dr][ns + j];
#pragma unroll
      for (int j = 0; j < 8; ++j) o1[j] = (_Float16)tile[rbase + dr][ns + 8 + j];
      _Float16* dst = xT + ((size_t)(b * ND + d0 + dr) * NN + n0 + ns);
      *(h8*)dst = o0;
      *(h8*)(dst + 8) = o1;
    }
    return;
  }

  // --------------- k2 role: Sinkhorn (r10 body verbatim) ---------------
  const int bh = bid;
  const int b = bh >> 2, h = bh & 3;
  const int lane = tid & 63;

  float* evf = sm.s2.evf;
  h2* evh = sm.s2.evh;
  unsigned int* pbuf = sm.s2.pbuf;

  const _Float16* Ep = E + (size_t)bh * (NN * NM);

  // rows 4*tid .. 4*tid+3 (adjacent: packs the Pt epilogue into 8B stores)
  h2 e[4][32];
#pragma unroll
  for (int i = 0; i < 4; ++i) {
    const uint4* src = (const uint4*)(Ep + (size_t)(4 * tid + i) * NM);
#pragma unroll
    for (int q = 0; q < 8; ++q) {
      uint4 v = src[q];
      e[i][q * 4 + 0] = __builtin_bit_cast(h2, v.x);
      e[i][q * 4 + 1] = __builtin_bit_cast(h2, v.y);
      e[i][q * 4 + 2] = __builtin_bit_cast(h2, v.z);
      e[i][q * 4 + 3] = __builtin_bit_cast(h2, v.w);
    }
  }

  float eu[4] = {1.f, 1.f, 1.f, 1.f};
  if (tid < 64) evf[tid] = 1.f;
  if (tid < 32) evh[tid] = pkrtz(1.f, 1.f);
  __syncthreads();

#pragma unroll 1
  for (int it = 0; it < NITER; ++it) {
    // broadcast ev (fp16-packed master in LDS)
    h2 evr[32];
    {
      const uint4* ev4 = (const uint4*)evh;
#pragma unroll
      for (int q8 = 0; q8 < 8; ++q8) {
        uint4 v = ev4[q8];
        evr[q8 * 4 + 0] = __builtin_bit_cast(h2, v.x);
        evr[q8 * 4 + 1] = __builtin_bit_cast(h2, v.y);
        evr[q8 * 4 + 2] = __builtin_bit_cast(h2, v.z);
        evr[q8 * 4 + 3] = __builtin_bit_cast(h2, v.w);
      }
    }
    // u-pass: S[n] = sum_m E*ev ; eu = (1/N)/(eu*S).  8 chains for ILP.
    float sa[4] = {0.f, 0.f, 0.f, 0.f};
    float sb[4] = {0.f, 0.f, 0.f, 0.f};
#pragma unroll
    for (int q = 0; q < 16; ++q) {
#pragma unroll
      for (int i = 0; i < 4; ++i) sa[i] = fdot2f(e[i][q], evr[q], sa[i]);
    }
#pragma unroll
    for (int q = 16; q < 32; ++q) {
#pragma unroll
      for (int i = 0; i < 4; ++i) sb[i] = fdot2f(e[i][q], evr[q], sb[i]);
    }
#pragma unroll
    for (int i = 0; i < 4; ++i) {
      eu[i] = 4.8828125e-4f * __builtin_amdgcn_rcpf(eu[i] * (sa[i] + sb[i]));
    }
    // v-pass local: T'[m] = sum_rows E * (eu*EUSCALE)
    h2 eup[4];
#pragma unroll
    for (int i = 0; i < 4; ++i) {
      const float es = eu[i] * EUSCALE;
      eup[i] = pkrtz(es, es);
    }
    h2 tp[32];
#pragma unroll
    for (int q = 0; q < 32; ++q) {
      tp[q] = e[0][q] * eup[0] + e[1][q] * eup[1];
      tp[q] += e[2][q] * eup[2] + e[3][q] * eup[3];
    }
    // register-halving butterfly: after 5 steps lane l holds wave-partial for
    // col-pair q = bitrev5(l&31); lanes l and l^32 hold the two half-sums.
#pragma unroll
    for (int k = 0; k < 5; ++k) {
      const int nn = 32 >> k;
      const bool up = (lane >> k) & 1;
#pragma unroll
      for (int p = 0; p < (nn >> 1); ++p) {
        h2 keep = up ? tp[p + (nn >> 1)] : tp[p];
        h2 send = up ? tp[p] : tp[p + (nn >> 1)];
        int rv = __shfl_xor(__builtin_bit_cast(int, send), 1 << k, 64);
        tp[p] = keep + __builtin_bit_cast(h2, rv);
      }
    }
    pbuf[tid] = __builtin_bit_cast(unsigned int, tp[0]);
    __syncthreads();
    if (tid < 32) {
      const int j = tid;
      const int rev = ((j & 1) << 4) | ((j & 2) << 2) | (j & 4) | ((j & 8) >> 2) | ((j & 16) >> 4);
      float T0 = 0.f, T1 = 0.f;
#pragma unroll
      for (int wq = 0; wq < 8; ++wq) {
        h2 a = __builtin_bit_cast(h2, pbuf[wq * 64 + rev]);
        h2 c = __builtin_bit_cast(h2, pbuf[wq * 64 + rev + 32]);
        T0 += (float)a[0] + (float)c[0];
        T1 += (float)a[1] + (float)c[1];
      }
      const float e0 = evf[2 * j], e1 = evf[2 * j + 1];
      // ev_new = 1/(ev_old*T) with T = T'/EUSCALE
      const float n0 = EUSCALE * __builtin_amdgcn_rcpf(e0 * T0);
      const float n1 = EUSCALE * __builtin_amdgcn_rcpf(e1 * T1);
      evf[2 * j] = n0;
      evf[2 * j + 1] = n1;
      evh[j] = pkrtz(n0, n1);
    }
    __syncthreads();
  }

  // epilogue: P = E*eu*ev, Pt[b][m][h][n] fp16; rows 4t..4t+3 -> 8B stores.
  _Float16* Pb = Pt + ((size_t)(b * 256 + h)) * NN;
#pragma unroll
  for (int q = 0; q < 32; ++q) {
    const float ev0 = evf[2 * q];
    const float ev1 = evf[2 * q + 1];
    float a0[4], a1[4];
#pragma unroll
    for (int i = 0; i < 4; ++i) {
      a0[i] = (float)e[i][q][0] * eu[i] * ev0;   // row 4t+i, col 2q
      a1[i] = (float)e[i][q][1] * eu[i] * ev1;   // row 4t+i, col 2q+1
    }
    uint2 st0, st1;
    st0.x = __builtin_bit_cast(unsigned int, pkrtz(a0[0], a0[1]));
    st0.y = __builtin_bit_cast(unsigned int, pkrtz(a0[2], a0[3]));
    st1.x = __builtin_bit_cast(unsigned int, pkrtz(a1[0], a1[1]));
    st1.y = __builtin_bit_cast(unsigned int, pkrtz(a1[2], a1[3]));
    *(uint2*)(Pb + (size_t)(2 * q) * 4 * NN + 4 * tid) = st0;
    *(uint2*)(Pb + (size_t)(2 * q + 1) * 4 * NN + 4 * tid) = st1;
  }
}

// ------------------------------------------------------------- k3: out GEMM
// 256 threads, 64x64 output tile, grid (8,4,16)=512 blocks (2/CU), register
// prefetch of the next K-tile hides global-load latency under the MFMAs.
__global__ __launch_bounds__(256) void k3_out(const _Float16* __restrict__ Pt,
                                              const _Float16* __restrict__ xT,
                                              float* __restrict__ out) {
  __shared__ _Float16 As[64][72];
  __shared__ _Float16 Bs[64][72];
  const int b = blockIdx.z;
  const int hf = blockIdx.y;
  const int dt = blockIdx.x;
  const int tid = threadIdx.x;
  const int lane = tid & 63;
  const int wv = tid >> 6;
  const int lrow = lane & 15;
  const int kq = lane >> 4;

  f4 acc[4];
#pragma unroll
  for (int i = 0; i < 4; ++i) acc[i] = (f4){0.f, 0.f, 0.f, 0.f};

  const int ar = tid >> 2, ac = (tid & 3) * 16;
  const _Float16* asrc = Pt + ((size_t)(b * 256 + hf * 64 + ar) * NN + ac);
  const _Float16* bsrc = xT + ((size_t)(b * ND + dt * 64 + ar) * NN + ac);

  h8 a0 = *(const h8*)(asrc);
  h8 a1 = *(const h8*)(asrc + 8);
  h8 b0 = *(const h8*)(bsrc);
  h8 b1 = *(const h8*)(bsrc + 8);

  for (int kt = 0; kt < 32; ++kt) {
    *(h8*)&As[ar][ac] = a0;
    *(h8*)&As[ar][ac + 8] = a1;
    *(h8*)&Bs[ar][ac] = b0;
    *(h8*)&Bs[ar][ac + 8] = b1;
    __syncthreads();
    if (kt < 31) {
      const int k0 = (kt + 1) * 64;
      a0 = *(const h8*)(asrc + k0);
      a1 = *(const h8*)(asrc + k0 + 8);
      b0 = *(const h8*)(bsrc + k0);
      b1 = *(const h8*)(bsrc + k0 + 8);
    }
#pragma unroll
    for (int s = 0; s < 2; ++s) {
      h8 af = *(const h8*)&As[wv * 16 + lrow][s * 32 + kq * 8];
#pragma unroll
      for (int cf = 0; cf < 4; ++cf) {
        h8 bf = *(const h8*)&Bs[cf * 16 + lrow][s * 32 + kq * 8];
        acc[cf] = __builtin_amdgcn_mfma_f32_16x16x32_f16(af, bf, acc[cf], 0, 0, 0);
      }
    }
    __syncthreads();
  }
#pragma unroll
  for (int cf = 0; cf < 4; ++cf) {
    const int d = dt * 64 + cf * 16 + lrow;
#pragma unroll
    for (int j = 0; j < 4; ++j) {
      const int row = hf * 64 + wv * 16 + kq * 4 + j;
      out[(size_t)(b * 256 + row) * ND + d] = acc[cf][j];
    }
  }
}

// ---------------------------------------------------------------- launcher
extern "C" void kernel_launch(void* const* d_in, const int* in_sizes, int n_in,
                              void* d_out, int out_size, void* d_ws, size_t ws_size,
                              hipStream_t stream) {
  const float* x = (const float*)d_in[0];
  const float* w = (const float*)d_in[1];
  float* out = (float*)d_out;
  char* ws = (char*)d_ws;
  // ws layout:
  //   xT : 16*512*2048 fp16 = 33,554,432 B
  //   E  : 16*4*2048*64 fp16 = 16,777,216 B
  //   Pt : 16*64*4*2048 fp16 = 16,777,216 B
  _Float16* xT = (_Float16*)ws;
  _Float16* E  = (_Float16*)(ws + (size_t)33554432);
  _Float16* Pt = (_Float16*)(ws + (size_t)50331648);

  k1_buildE<<<dim3(16, NB), 512, 0, stream>>>(x, w, E);
  k20_fused<<<64 + 1024, 512, 0, stream>>>(x, E, xT, Pt);
  k3_out<<<dim3(8, 4, NB), 256, 0, stream>>>(Pt, xT, out);
}